// Round 17
// baseline (80.766 us; speedup 1.0000x reference)
//
#include <hip/hip_runtime.h>

typedef __attribute__((ext_vector_type(8))) _Float16 f16x8_t;  // MFMA A/B operand (4 VGPRs)
typedef __attribute__((ext_vector_type(2))) _Float16 f16x2_t;  // packed f16 pair
typedef __attribute__((ext_vector_type(4))) float f32x4_t;     // MFMA accumulator

#define SLOTS 64
#define OVF_CAP 8192

__device__ __forceinline__ f16x2_t pkh(float lo, float hi) {
    return __builtin_bit_cast(f16x2_t, __builtin_amdgcn_cvt_pkrtz(lo, hi));
}
__device__ __forceinline__ unsigned int pkrtz(float lo, float hi) {
    return __builtin_bit_cast(unsigned int, __builtin_amdgcn_cvt_pkrtz(lo, hi));
}

#define LD4(p) (*reinterpret_cast<const float4*>(p))

// ws layout (bytes):
//   [0      ..  19456)  f16 tab: W1p (2KB) + W2p (17KB)
//   [65536  .. 265536)  int cnt[n_nodes]
//   [327680 .. 327684)  int ovf_cnt
//   [327744 .. 360512)  int ovf[OVF_CAP]
//   [512K   .. +12.8MB) int eord[n_nodes][SLOTS]
//   [16MB   .. +32MB)   float msg[E][16]

// ============ kernel 0: {root-init + cnt zero | tab prep + ovf_cnt zero} ============
__global__ __launch_bounds__(256) void prep_kernel(
    const float* __restrict__ x,
    const float* __restrict__ W1,      // [8,32]
    const float* __restrict__ b1,      // [32]
    const float* __restrict__ W2,      // [32,256]
    const float* __restrict__ b2,      // [256]
    const float* __restrict__ rootk,   // [16,16]
    const float* __restrict__ bias,    // [16]
    float* __restrict__ out,           // [N,16]
    _Float16* __restrict__ tab,
    int* __restrict__ cnt,             // may be null (fallback mode)
    int* __restrict__ ovf_cnt,
    int n_nodes, int root_blocks)
{
    const int tid = threadIdx.x;
    const int bid = blockIdx.x;

    if (bid < root_blocks) {
        __shared__ float sR[256];
        __shared__ float sB[16];
        if (tid < 256) sR[tid] = rootk[tid];
        if (tid < 16)  sB[tid] = bias[tid];
        __syncthreads();

        int nid = bid * 256 + tid;
        if (nid >= n_nodes) return;
        if (cnt) cnt[nid] = 0;

        const float* xp = x + (size_t)nid * 16;
        float xf[16];
#pragma unroll
        for (int f = 0; f < 16; f += 4) {
            float4 v = LD4(xp + f);
            xf[f] = v.x; xf[f + 1] = v.y; xf[f + 2] = v.z; xf[f + 3] = v.w;
        }
        float o[16];
#pragma unroll
        for (int cc = 0; cc < 16; ++cc) o[cc] = sB[cc];
#pragma unroll
        for (int f = 0; f < 16; ++f) {
            float p = xf[f];
#pragma unroll
            for (int cc = 0; cc < 16; ++cc)
                o[cc] = fmaf(p, sR[f * 16 + cc], o[cc]);
        }
        float* dst = out + (size_t)nid * 16;
#pragma unroll
        for (int cc = 0; cc < 16; cc += 4)
            *reinterpret_cast<float4*>(dst + cc) = make_float4(o[cc], o[cc+1], o[cc+2], o[cc+3]);
    } else {
        if (tid == 0 && ovf_cnt) *ovf_cnt = 0;
        for (int it = tid; it < 64 * 19; it += 256) {
            int grp  = it >> 6;         // 0,1 -> W1p halves; 2..18 -> W2p steps
            int lane = it & 63;
            int q = lane >> 4, cc = lane & 15;
            union { _Float16 h[8]; uint4 u; } pk;
            if (grp < 2) {
                int hh = grp;
#pragma unroll
                for (int j = 0; j < 8; ++j) {
                    float v = 0.f;
                    if (q == 0)              v = W1[j * 32 + cc + 16 * hh];
                    else if (q == 1 && j==0) v = b1[cc + 16 * hh];
                    pk.h[j] = (_Float16)v;
                }
                *reinterpret_cast<uint4*>(tab + ((size_t)hh * 64 + lane) * 8) = pk.u;
            } else {
                int s = grp - 2;        // K-step
#pragma unroll
                for (int j = 0; j < 8; ++j) {
                    float v;
                    if (s < 16) {
                        int hd = (j < 4) ? (4 * q + j) : (4 * q + 12 + j);  // perm
                        v = W2[hd * 256 + s * 16 + cc];
                    } else {
                        v = (q < 2) ? b2[(q * 8 + j) * 16 + cc] : 0.f;       // b2 fold
                    }
                    pk.h[j] = (_Float16)v;
                }
                *reinterpret_cast<uint4*>(tab + 1024 + ((size_t)s * 64 + lane) * 8) = pk.u;
            }
        }
    }
}

// ============ kernel 1: bucket edges by target ============
__global__ __launch_bounds__(256) void bucket_kernel(
    const int* __restrict__ idx_i,
    int* __restrict__ cnt,
    int* __restrict__ eord,
    int* __restrict__ ovf_cnt,
    int* __restrict__ ovf,
    int n_edges)
{
    int e = blockIdx.x * 256 + threadIdx.x;
    if (e >= n_edges) return;
    int t = idx_i[e];
    int pos = atomicAdd(cnt + t, 1);
    if (pos < SLOTS) {
        eord[(size_t)t * SLOTS + pos] = e;
    } else {
        int o = atomicAdd(ovf_cnt, 1);
        if (o < OVF_CAP) ovf[o] = e;
    }
}

// ============ kernel 2: MFMA edge kernel — NO scatter; streams msg[e][16] ============
// MSG=1: write msg stream.  MSG=0 (fallback): direct atomic scatter to out.
template<int MSG, int EXACT>
__global__ __launch_bounds__(256) void edge_mfma_kernel(
    const float* __restrict__ x,       // [N,16]
    const float* __restrict__ efeat,   // [E,8]
    const int*   __restrict__ idx_i,   // (MSG=0 only)
    const int*   __restrict__ idx_j,
    const _Float16* __restrict__ tab,
    float* __restrict__ msg,           // [E][16]  (MSG=1)
    float* __restrict__ out,           // [N,16]   (MSG=0)
    int n_edges, int n_groups)
{
    const int lane = threadIdx.x & 63;
    const int q = lane >> 4;
    const int c = lane & 15;

    // ---- per-wave fragment preload (registers, f16) ----
    const f16x8_t* w1f = reinterpret_cast<const f16x8_t*>(tab) + lane;
    const f16x8_t aW1_0 = w1f[0];
    const f16x8_t aW1_1 = w1f[64];
    const f16x8_t* w2f = reinterpret_cast<const f16x8_t*>(tab + 1024) + lane;
    f16x8_t bW2[17];
#pragma unroll
    for (int s = 0; s < 17; ++s) bW2[s] = w2f[s * 64];

    const unsigned int c1 = (q == 1) ? 0x00003C00u : 0u;   // f16(1.0) one-hot for b1 row
    const bool isq0 = (q == 0);
    const bool qodd = (q & 1);

    const int nwaves = gridDim.x * 4;
    for (int g = blockIdx.x * 4 + (threadIdx.x >> 6); g < n_groups; g += nwaves) {
        int eid = g * 16 + c;
        bool va = (eid < n_edges);
        int el = va ? eid : (n_edges - 1);
        int j = idx_j[el];

        const float* xp = x + (size_t)j * 16;
        float4 X0 = LD4(xp), X1 = LD4(xp + 4), X2 = LD4(xp + 8), X3 = LD4(xp + 12);
        const float* ep = efeat + (size_t)el * 8;
        float4 E0 = LD4(ep), E1 = LD4(ep + 4);

        union { f16x8_t v8; unsigned int u[4]; } bB;
        bB.u[0] = isq0 ? pkrtz(E0.x, E0.y) : c1;
        bB.u[1] = isq0 ? pkrtz(E0.z, E0.w) : 0u;
        bB.u[2] = isq0 ? pkrtz(E1.x, E1.y) : 0u;
        bB.u[3] = isq0 ? pkrtz(E1.z, E1.w) : 0u;
        f32x4_t z4 = {0.f, 0.f, 0.f, 0.f};
        f32x4_t h0 = __builtin_amdgcn_mfma_f32_16x16x32_f16(aW1_0, bB.v8, z4, 0, 0, 0);
        f32x4_t h1 = __builtin_amdgcn_mfma_f32_16x16x32_f16(aW1_1, bB.v8, z4, 0, 0, 0);

        f16x2_t hp0 = pkh(fmaxf(h0[0], 0.f), fmaxf(h0[1], 0.f));
        f16x2_t hp1 = pkh(fmaxf(h0[2], 0.f), fmaxf(h0[3], 0.f));
        f16x2_t hp2 = pkh(fmaxf(h1[0], 0.f), fmaxf(h1[1], 0.f));
        f16x2_t hp3 = pkh(fmaxf(h1[2], 0.f), fmaxf(h1[3], 0.f));

        float xf[16];
        xf[0]=X0.x; xf[1]=X0.y; xf[2]=X0.z; xf[3]=X0.w;
        xf[4]=X1.x; xf[5]=X1.y; xf[6]=X1.z; xf[7]=X1.w;
        xf[8]=X2.x; xf[9]=X2.y; xf[10]=X2.z; xf[11]=X2.w;
        xf[12]=X3.x; xf[13]=X3.y; xf[14]=X3.z; xf[15]=X3.w;
        if (!EXACT && !va) {
#pragma unroll
            for (int t = 0; t < 16; ++t) xf[t] = 0.f;
        }

        f16x2_t xss[16];
#pragma unroll
        for (int f = 0; f < 16; ++f) xss[f] = pkh(xf[f], xf[f]);

        union { f16x8_t v8; unsigned int u[4]; } xb;
        xb.u[0] = pkrtz(qodd ? xf[8]  : xf[0], qodd ? xf[9]  : xf[1]);
        xb.u[1] = pkrtz(qodd ? xf[10] : xf[2], qodd ? xf[11] : xf[3]);
        xb.u[2] = pkrtz(qodd ? xf[12] : xf[4], qodd ? xf[13] : xf[5]);
        xb.u[3] = pkrtz(qodd ? xf[14] : xf[6], qodd ? xf[15] : xf[7]);

        f32x4_t acc0 = {0.f,0.f,0.f,0.f}, acc1 = {0.f,0.f,0.f,0.f};
        union { f16x8_t v8; f16x2_t v2[4]; } afr;
#pragma unroll
        for (int s = 0; s < 16; s += 2) {
            f16x2_t xs2 = xss[s];
            afr.v2[0] = hp0 * xs2; afr.v2[1] = hp1 * xs2;
            afr.v2[2] = hp2 * xs2; afr.v2[3] = hp3 * xs2;
            acc0 = __builtin_amdgcn_mfma_f32_16x16x32_f16(afr.v8, bW2[s], acc0, 0, 0, 0);
            xs2 = xss[s + 1];
            afr.v2[0] = hp0 * xs2; afr.v2[1] = hp1 * xs2;
            afr.v2[2] = hp2 * xs2; afr.v2[3] = hp3 * xs2;
            acc1 = __builtin_amdgcn_mfma_f32_16x16x32_f16(afr.v8, bW2[s + 1], acc1, 0, 0, 0);
        }
        acc0 = __builtin_amdgcn_mfma_f32_16x16x32_f16(xb.v8, bW2[16], acc0, 0, 0, 0);

        const float rr0 = acc0[0] + acc1[0];
        const float rr1 = acc0[1] + acc1[1];
        const float rr2 = acc0[2] + acc1[2];
        const float rr3 = acc0[3] + acc1[3];
        const int eb = g * 16 + q * 4;

        if (MSG) {
            // coalesced stream: quadrant q's 16 lanes fill one 64B line per row
            float* mp = msg + (size_t)eb * 16 + c;
            if (EXACT || (eb + 0 < n_edges)) mp[0]  = rr0;
            if (EXACT || (eb + 1 < n_edges)) mp[16] = rr1;
            if (EXACT || (eb + 2 < n_edges)) mp[32] = rr2;
            if (EXACT || (eb + 3 < n_edges)) mp[48] = rr3;
        } else {
            int t0 = (EXACT || eb + 0 < n_edges) ? idx_i[eb + 0] : 0;
            int t1 = (EXACT || eb + 1 < n_edges) ? idx_i[eb + 1] : 0;
            int t2 = (EXACT || eb + 2 < n_edges) ? idx_i[eb + 2] : 0;
            int t3 = (EXACT || eb + 3 < n_edges) ? idx_i[eb + 3] : 0;
            float* outc = out + c;
            if (EXACT || eb + 0 < n_edges) atomicAdd(outc + (size_t)t0 * 16, rr0);
            if (EXACT || eb + 1 < n_edges) atomicAdd(outc + (size_t)t1 * 16, rr1);
            if (EXACT || eb + 2 < n_edges) atomicAdd(outc + (size_t)t2 * 16, rr2);
            if (EXACT || eb + 3 < n_edges) atomicAdd(outc + (size_t)t3 * 16, rr3);
        }
    }
}

// ============ kernel 3: per-(node,channel) gather-sum — random-line READS only ============
__global__ __launch_bounds__(256) void gather_kernel(
    const float* __restrict__ msg,     // [E][16]
    const int*   __restrict__ cnt,
    const int*   __restrict__ eord,    // [N][SLOTS]
    float* __restrict__ out,
    int n_nodes)
{
    int gi = blockIdx.x * 256 + threadIdx.x;
    int n = gi >> 4;
    int c = gi & 15;
    if (n >= n_nodes) return;

    int m = cnt[n];
    m = (m < SLOTS) ? m : SLOTS;
    const int* ep = eord + (size_t)n * SLOTS;

    float s0 = 0.f, s1 = 0.f;
    int k = 0;
    for (; k + 4 <= m; k += 4) {
        int4 ev = *reinterpret_cast<const int4*>(ep + k);
        float v0 = msg[(size_t)ev.x * 16 + c];
        float v1 = msg[(size_t)ev.y * 16 + c];
        float v2 = msg[(size_t)ev.z * 16 + c];
        float v3 = msg[(size_t)ev.w * 16 + c];
        s0 += v0 + v2;
        s1 += v1 + v3;
    }
    for (; k < m; ++k) s0 += msg[(size_t)ep[k] * 16 + c];
    out[(size_t)n * 16 + c] += s0 + s1;
}

// ============ kernel 4: overflow tail (deg > SLOTS) — normally zero work ============
__global__ __launch_bounds__(256) void ovf_kernel(
    const float* __restrict__ msg,
    const int*   __restrict__ idx_i,
    const int*   __restrict__ ovf_cnt,
    const int*   __restrict__ ovf,
    float* __restrict__ out)
{
    int m = *ovf_cnt;
    if (m > OVF_CAP) m = OVF_CAP;
    for (int it = threadIdx.x + blockIdx.x * 256; it < m * 16; it += gridDim.x * 256) {
        int o = it >> 4, c = it & 15;
        int e = ovf[o];
        int t = idx_i[e];
        atomicAdd(out + (size_t)t * 16 + c, msg[(size_t)e * 16 + c]);
    }
}

extern "C" void kernel_launch(void* const* d_in, const int* in_sizes, int n_in,
                              void* d_out, int out_size, void* d_ws, size_t ws_size,
                              hipStream_t stream) {
    const float* x     = (const float*)d_in[0];
    const float* e     = (const float*)d_in[1];
    const int*   idx_i = (const int*)d_in[2];
    const int*   idx_j = (const int*)d_in[3];
    const float* W1    = (const float*)d_in[4];
    const float* b1    = (const float*)d_in[5];
    const float* W2    = (const float*)d_in[6];
    const float* b2    = (const float*)d_in[7];
    const float* rootk = (const float*)d_in[8];
    const float* bias  = (const float*)d_in[9];

    int n_nodes  = in_sizes[0] / 16;
    int n_edges  = in_sizes[2];
    int n_groups = (n_edges + 15) / 16;

    float* out = (float*)d_out;
    _Float16* tab = (_Float16*)d_ws;
    int* cnt     = (int*)((char*)d_ws + 65536);
    int* ovf_cnt = (int*)((char*)d_ws + 327680);
    int* ovf     = (int*)((char*)d_ws + 327744);
    int* eord    = (int*)((char*)d_ws + 524288);
    float* msg   = (float*)((char*)d_ws + (16u << 20));

    size_t need = (16u << 20) + (size_t)n_edges * 16 * sizeof(float);
    const int use_msg = (ws_size >= need &&
                         524288 + (size_t)n_nodes * SLOTS * 4 <= (16u << 20)) ? 1 : 0;

    int root_blocks = (n_nodes + 255) / 256;
    prep_kernel<<<root_blocks + 1, 256, 0, stream>>>(x, W1, b1, W2, b2, rootk, bias,
                                                     out, tab, use_msg ? cnt : nullptr,
                                                     use_msg ? ovf_cnt : nullptr,
                                                     n_nodes, root_blocks);

    if (use_msg) {
        int bblocks = (n_edges + 255) / 256;
        bucket_kernel<<<bblocks, 256, 0, stream>>>(idx_i, cnt, eord, ovf_cnt, ovf, n_edges);
        if ((n_edges & 15) == 0)
            edge_mfma_kernel<1, 1><<<1024, 256, 0, stream>>>(x, e, idx_i, idx_j, tab,
                                                             msg, out, n_edges, n_groups);
        else
            edge_mfma_kernel<1, 0><<<1024, 256, 0, stream>>>(x, e, idx_i, idx_j, tab,
                                                             msg, out, n_edges, n_groups);
        int gblocks = (n_nodes * 16 + 255) / 256;
        gather_kernel<<<gblocks, 256, 0, stream>>>(msg, cnt, eord, out, n_nodes);
        ovf_kernel<<<32, 256, 0, stream>>>(msg, idx_i, ovf_cnt, ovf, out);
    } else {
        edge_mfma_kernel<0, 0><<<1024, 256, 0, stream>>>(x, e, idx_i, idx_j, tab,
                                                         msg, out, n_edges, n_groups);
    }
}